// Round 1
// baseline (302.302 us; speedup 1.0000x reference)
//
#include <hip/hip_runtime.h>
#include <hip/hip_bf16.h>
#include <cstdint>

#define B_DIM 8192
#define D_DIM 512
#define BM 128
#define BN 128
#define BK 32

typedef __attribute__((ext_vector_type(8))) short bf16x8;
typedef __attribute__((ext_vector_type(4))) float f32x4;

typedef __attribute__((address_space(1))) const void* gas_ptr;
typedef __attribute__((address_space(3))) void* las_ptr;

static __device__ __forceinline__ unsigned short f2bf(float x) {
    __hip_bfloat16 h = __float2bfloat16(x);
    return *reinterpret_cast<unsigned short*>(&h);
}

// One wave per row: L2-normalize (f32) and emit bf16.
__global__ __launch_bounds__(256) void normalize_rows(
    const float* __restrict__ V, const float* __restrict__ T,
    unsigned short* __restrict__ Vn, unsigned short* __restrict__ Tn)
{
    const int wave = threadIdx.x >> 6;
    const int lane = threadIdx.x & 63;
    const int row = blockIdx.x * 4 + wave;     // 0..16383 (V rows then T rows)
    const float* src;
    unsigned short* dst;
    if (row < B_DIM) {
        src = V + (size_t)row * D_DIM;
        dst = Vn + (size_t)row * D_DIM;
    } else {
        src = T + (size_t)(row - B_DIM) * D_DIM;
        dst = Tn + (size_t)(row - B_DIM) * D_DIM;
    }
    float4 a = *(const float4*)(src + lane * 4);
    float4 b = *(const float4*)(src + 256 + lane * 4);
    float ss = a.x*a.x + a.y*a.y + a.z*a.z + a.w*a.w
             + b.x*b.x + b.y*b.y + b.z*b.z + b.w*b.w;
    #pragma unroll
    for (int off = 32; off; off >>= 1) ss += __shfl_xor(ss, off);
    const float inv = 1.0f / fmaxf(sqrtf(ss), 1e-12f);
    ushort4 oa, ob;
    oa.x = f2bf(a.x * inv); oa.y = f2bf(a.y * inv);
    oa.z = f2bf(a.z * inv); oa.w = f2bf(a.w * inv);
    ob.x = f2bf(b.x * inv); ob.y = f2bf(b.y * inv);
    ob.z = f2bf(b.z * inv); ob.w = f2bf(b.w * inv);
    *(ushort4*)(dst + lane * 4) = oa;
    *(ushort4*)(dst + 256 + lane * 4) = ob;
}

// 128x128 tile NT GEMM (m97 structure) with fused epilogue:
// writes similarities + negative_mask, accumulates masked exp row-sums.
__global__ __launch_bounds__(256) void gemm_fused(
    const unsigned short* __restrict__ Vn, const unsigned short* __restrict__ Tn,
    const int* __restrict__ noisy,
    float* __restrict__ sim_out, float* __restrict__ mask_out,
    float* __restrict__ rowsum)
{
    __shared__ unsigned short Al[BM * BK];   // [128][32] bf16, linear
    __shared__ unsigned short Bl[BN * BK];

    const int tid  = threadIdx.x;
    const int wave = tid >> 6;
    const int lane = tid & 63;
    const int wr = wave >> 1;       // wave row (0..1)
    const int wc = wave & 1;        // wave col (0..1)

    // XCD-aware swizzle: 4096 blocks, 4096 % 8 == 0 -> bijective.
    const int bid = blockIdx.x;
    const int swz = (bid & 7) * (4096 / 8) + (bid >> 3);
    const int brow = (swz >> 6) * BM;
    const int bcol = (swz & 63) * BN;

    // staging: each wave issues 2 x global_load_lds(16B) per matrix per K-step.
    const int sr = lane >> 2;          // row within a 16-row chunk
    const int sc = (lane & 3) * 8;     // col (bf16 elements)
    const int c0 = wave * 2;

    f32x4 acc[4][4] = {};              // 64 f32 accumulators

    const int fr = lane & 15;
    const int ko = (lane >> 4) * 8;

    for (int k0 = 0; k0 < D_DIM; k0 += BK) {
        #pragma unroll
        for (int q = 0; q < 2; ++q) {
            const int cw  = c0 + q;
            const int row = cw * 16 + sr;
            const unsigned short* ga = Vn + (size_t)(brow + row) * D_DIM + k0 + sc;
            const unsigned short* gb = Tn + (size_t)(bcol + row) * D_DIM + k0 + sc;
            __builtin_amdgcn_global_load_lds((gas_ptr)ga, (las_ptr)&Al[cw * 512], 16, 0, 0);
            __builtin_amdgcn_global_load_lds((gas_ptr)gb, (las_ptr)&Bl[cw * 512], 16, 0, 0);
        }
        __syncthreads();

        bf16x8 af[4], bfr[4];
        #pragma unroll
        for (int m = 0; m < 4; ++m)
            af[m] = *(const bf16x8*)&Al[(wr * 64 + m * 16 + fr) * BK + ko];
        #pragma unroll
        for (int n = 0; n < 4; ++n)
            bfr[n] = *(const bf16x8*)&Bl[(wc * 64 + n * 16 + fr) * BK + ko];

        #pragma unroll
        for (int m = 0; m < 4; ++m)
            #pragma unroll
            for (int n = 0; n < 4; ++n)
                acc[m][n] = __builtin_amdgcn_mfma_f32_16x16x32_bf16(
                    af[m], bfr[n], acc[m][n], 0, 0, 0);
        __syncthreads();
    }

    // ---- fused epilogue ----
    const float Tinv = 1.0f / 0.07f;
    const int cg = lane >> 4;           // C/D row group
    const int ci = lane & 15;           // C/D col within fragment
    int coln[4];
    #pragma unroll
    for (int n = 0; n < 4; ++n)
        coln[n] = noisy[bcol + wc * 64 + n * 16 + ci];

    #pragma unroll
    for (int m = 0; m < 4; ++m) {
        #pragma unroll
        for (int r = 0; r < 4; ++r) {
            const int grow = brow + wr * 64 + m * 16 + cg * 4 + r;
            const int rn = noisy[grow];
            const size_t rowoff = (size_t)grow * B_DIM;
            float partial = 0.0f;
            #pragma unroll
            for (int n = 0; n < 4; ++n) {
                const int gcol = bcol + wc * 64 + n * 16 + ci;
                const float s  = acc[m][n][r];
                const float mk = (rn | coln[n]) ? 1.0f : 0.0f;
                sim_out[rowoff + gcol]  = s;
                mask_out[rowoff + gcol] = mk;
                partial += __expf(s * Tinv) * mk;
            }
            // reduce across the 16 lanes sharing this output row
            partial += __shfl_xor(partial, 1);
            partial += __shfl_xor(partial, 2);
            partial += __shfl_xor(partial, 4);
            partial += __shfl_xor(partial, 8);
            if (ci == 0) atomicAdd(&rowsum[grow], partial);
        }
    }
}

__global__ __launch_bounds__(256) void loss_reduce(
    const float* __restrict__ rowsum, float* __restrict__ out)
{
    __shared__ float wsum[4];
    float s = 0.0f;
    for (int i = threadIdx.x; i < B_DIM; i += 256)
        s += logf(rowsum[i] + 1e-8f);
    #pragma unroll
    for (int off = 32; off; off >>= 1) s += __shfl_xor(s, off);
    if ((threadIdx.x & 63) == 0) wsum[threadIdx.x >> 6] = s;
    __syncthreads();
    if (threadIdx.x == 0) {
        const float t = (wsum[0] + wsum[1]) + (wsum[2] + wsum[3]);
        const float loss = t * (1.0f / (float)B_DIM);
        out[0] = loss;   // complementary_loss
        out[1] = loss;   // brownian_loss (identical chain)
    }
}

extern "C" void kernel_launch(void* const* d_in, const int* in_sizes, int n_in,
                              void* d_out, int out_size, void* d_ws, size_t ws_size,
                              hipStream_t stream) {
    const float* V = (const float*)d_in[0];
    const float* T = (const float*)d_in[1];
    const int* noisy = (const int*)d_in[3];   // confident_clean_mask (d_in[2]) unused
    float* out = (float*)d_out;

    float* mask_out = out + 2;
    float* sim_out  = out + 2 + (size_t)B_DIM * B_DIM;

    unsigned short* Vn = (unsigned short*)d_ws;                       // 8 MB
    unsigned short* Tn = Vn + (size_t)B_DIM * D_DIM;                  // 8 MB
    float* rowsum = (float*)(Tn + (size_t)B_DIM * D_DIM);             // 32 KB

    hipMemsetAsync(rowsum, 0, B_DIM * sizeof(float), stream);
    normalize_rows<<<(2 * B_DIM) / 4, 256, 0, stream>>>(V, T, Vn, Tn);
    gemm_fused<<<64 * 64, 256, 0, stream>>>(Vn, Tn, noisy, sim_out, mask_out, rowsum);
    loss_reduce<<<1, 256, 0, stream>>>(rowsum, out);
}